// Round 2
// baseline (659.094 us; speedup 1.0000x reference)
//
#include <hip/hip_runtime.h>

using f16 = _Float16;
typedef f16 f16x8 __attribute__((ext_vector_type(8)));
typedef f16 f16x4 __attribute__((ext_vector_type(4)));
typedef float f32x4 __attribute__((ext_vector_type(4)));

#define TOKENS 4096   // B*N
#define KD 2048       // 2*DIM  (GEMM inner dim, k = 2*dk + ck)
#define NQ 6144       // qkv output cols (3*DIM complex -> which*2048 + h*128 + d*2 + c)
#define ATT_SCALE 0.125f

__device__ __forceinline__ void gload_lds16(const void* g, void* l) {
  __builtin_amdgcn_global_load_lds(
      (__attribute__((address_space(1))) void*)(unsigned long long)g,
      (__attribute__((address_space(3))) void*)l, 16, 0, 0);
}

// ---------------- prep kernels ----------------
__global__ __launch_bounds__(256) void cast_x_kernel(const float* __restrict__ x,
                                                     f16* __restrict__ X, int n) {
  int i = blockIdx.x * 256 + threadIdx.x;
  if (i < n) X[i] = (f16)x[i];
}

// Wp[j][k]: j = which*2048 + h*128 + d*2 + c  (o = which*1024 + h*64 + d)
// k = 2*dk + ck.  out_r needs [wr ; -wi], out_i needs [wi ; wr]. bias folded.
__global__ __launch_bounds__(256) void pack_wqkv_kernel(const float* __restrict__ wr,
    const float* __restrict__ wi, const float* __restrict__ br, const float* __restrict__ bi,
    f16* __restrict__ Wp, float* __restrict__ biasq) {
  int idx = blockIdx.x * 256 + threadIdx.x;
  if (idx >= NQ * KD) return;
  int j = idx >> 11;
  int k = idx & 2047;
  int which = j >> 11;
  int rem = j & 2047;
  int h = rem >> 7, t = rem & 127, d = t >> 1, c = t & 1;
  int o = which * 1024 + h * 64 + d;
  int dk = k >> 1, ck = k & 1;
  float wrv = wr[o * 1024 + dk], wiv = wi[o * 1024 + dk];
  float v = (c == 0) ? ((ck == 0) ? wrv : -wiv) : ((ck == 0) ? wiv : wrv);
  Wp[idx] = (f16)v;
  if (k == 0) biasq[j] = (c == 0) ? (br[o] - bi[o]) : (br[o] + bi[o]);
}

// Wo_p[j][k]: j = 2*jo + c
__global__ __launch_bounds__(256) void pack_wo_kernel(const float* __restrict__ wr,
    const float* __restrict__ wi, const float* __restrict__ br, const float* __restrict__ bi,
    f16* __restrict__ Wp, float* __restrict__ biaso) {
  int idx = blockIdx.x * 256 + threadIdx.x;
  if (idx >= KD * KD) return;
  int j = idx >> 11, k = idx & 2047;
  int jo = j >> 1, c = j & 1;
  int dk = k >> 1, ck = k & 1;
  float wrv = wr[jo * 1024 + dk], wiv = wi[jo * 1024 + dk];
  float v = (c == 0) ? ((ck == 0) ? wrv : -wiv) : ((ck == 0) ? wiv : wrv);
  Wp[idx] = (f16)v;
  if (k == 0) biaso[j] = (c == 0) ? (br[jo] - bi[jo]) : (br[jo] + bi[jo]);
}

// ---------------- GEMM: C[m][n] = sum_k A[m][k]*B[n][k] + bias[n] ----------------
// 128x128 tile, BK=32, 4 waves (2x2), each wave 64x64 = 4x4 MFMA 16x16x32 frags.
template<bool HALF_OUT>
__global__ __launch_bounds__(256) void gemm_tn(const f16* __restrict__ A,
    const f16* __restrict__ B, const float* __restrict__ bias,
    void* __restrict__ Cout, int N) {
  __shared__ f16 ldsA[128 * 32];
  __shared__ f16 ldsB[128 * 32];
  const int tid = threadIdx.x;
  const int wave = tid >> 6, lane = tid & 63;
  const int lo = lane & 15, hi = lane >> 4;
  const int m0 = blockIdx.y * 128, n0 = blockIdx.x * 128;
  const int wm = wave >> 1, wn = wave & 1;

  // staging: each wave covers 2 chunks of 16 rows x 32 halfs (1 KiB linear LDS each)
  const int srow = wave * 32 + (lane >> 2);
  const int scol = (lane & 3) * 8;
  const f16* gA0 = A + (size_t)(m0 + srow) * KD + scol;
  const f16* gA1 = gA0 + (size_t)16 * KD;
  const f16* gB0 = B + (size_t)(n0 + srow) * KD + scol;
  const f16* gB1 = gB0 + (size_t)16 * KD;
  f16* lA0 = &ldsA[wave * 1024];
  f16* lA1 = &ldsA[wave * 1024 + 512];
  f16* lB0 = &ldsB[wave * 1024];
  f16* lB1 = &ldsB[wave * 1024 + 512];

  f32x4 acc[4][4] = {};

  for (int kt = 0; kt < KD; kt += 32) {
    gload_lds16(gA0, lA0);
    gload_lds16(gA1, lA1);
    gload_lds16(gB0, lB0);
    gload_lds16(gB1, lB1);
    gA0 += 32; gA1 += 32; gB0 += 32; gB1 += 32;
    __syncthreads();   // drains vmcnt -> LDS tiles ready
    f16x8 af[4], bf[4];
    #pragma unroll
    for (int mi = 0; mi < 4; ++mi)
      af[mi] = *(const f16x8*)&ldsA[(wm * 64 + mi * 16 + lo) * 32 + hi * 8];
    #pragma unroll
    for (int ni = 0; ni < 4; ++ni)
      bf[ni] = *(const f16x8*)&ldsB[(wn * 64 + ni * 16 + lo) * 32 + hi * 8];
    #pragma unroll
    for (int mi = 0; mi < 4; ++mi)
      #pragma unroll
      for (int ni = 0; ni < 4; ++ni)
        acc[mi][ni] = __builtin_amdgcn_mfma_f32_16x16x32_f16(af[mi], bf[ni], acc[mi][ni], 0, 0, 0);
    __syncthreads();   // before next stage overwrites LDS
  }

  #pragma unroll
  for (int mi = 0; mi < 4; ++mi) {
    #pragma unroll
    for (int ni = 0; ni < 4; ++ni) {
      const int col = n0 + wn * 64 + ni * 16 + lo;
      const float bv = bias[col];
      #pragma unroll
      for (int r = 0; r < 4; ++r) {
        const int row = m0 + wm * 64 + mi * 16 + hi * 4 + r;  // D: row = 4*hi + r, col = lo
        const float v = acc[mi][ni][r] + bv;
        if (HALF_OUT) ((f16*)Cout)[(size_t)row * N + col] = (f16)v;
        else          ((float*)Cout)[(size_t)row * N + col] = v;
      }
    }
  }
}

// ---------------- flash attention, per (b,h), wave = 16 q-rows ----------------
// Swapped QK^T: S^T = mfma(K,Q) => lane holds S[q=lo][m = t*16 + 4*hi + r].
// P is then directly the A-fragment of mfma_f32_16x16x16f16 for PV (k = m = 4*hi+j).
__global__ __launch_bounds__(256) void attn_kernel(const f16* __restrict__ qkv,
                                                   f16* __restrict__ outp) {
  const int wave = threadIdx.x >> 6, lane = threadIdx.x & 63;
  const int lo = lane & 15, hi = lane >> 4;
  const int b = blockIdx.y >> 4, h = blockIdx.y & 15;
  const int q0 = blockIdx.x * 64 + wave * 16;

  const f16* base = qkv + (size_t)b * 2048 * NQ + h * 128;
  const f16* Qb = base;
  const f16* Kb = base + 2048;
  const f16* Vb = base + 4096;

  f16x8 qf[4];
  #pragma unroll
  for (int c = 0; c < 4; ++c)
    qf[c] = *(const f16x8*)(Qb + (size_t)(q0 + lo) * NQ + c * 32 + hi * 8);

  f32x4 o[8];
  #pragma unroll
  for (int dc = 0; dc < 8; ++dc) o[dc] = (f32x4){0.f, 0.f, 0.f, 0.f};
  float m_run = -INFINITY, l_run = 0.f;

  for (int t = 0; t < 2048; t += 16) {
    f32x4 s = {0.f, 0.f, 0.f, 0.f};
    #pragma unroll
    for (int c = 0; c < 4; ++c) {
      f16x8 kf = *(const f16x8*)(Kb + (size_t)(t + lo) * NQ + c * 32 + hi * 8);
      s = __builtin_amdgcn_mfma_f32_16x16x32_f16(kf, qf[c], s, 0, 0, 0);
    }
    #pragma unroll
    for (int r = 0; r < 4; ++r) s[r] *= ATT_SCALE;

    // row (q) reduction: q = lo fixed per lane, m spread over regs and hi-groups
    float pm = fmaxf(fmaxf(s[0], s[1]), fmaxf(s[2], s[3]));
    pm = fmaxf(pm, __shfl_xor(pm, 16));
    pm = fmaxf(pm, __shfl_xor(pm, 32));
    const float mn = fmaxf(m_run, pm);
    const float corr = __expf(m_run - mn);   // exp(-inf)=0 on first tile
    m_run = mn;

    float p[4], psum = 0.f;
    #pragma unroll
    for (int r = 0; r < 4; ++r) { p[r] = __expf(s[r] - mn); psum += p[r]; }
    psum += __shfl_xor(psum, 16);
    psum += __shfl_xor(psum, 32);
    l_run = l_run * corr + psum;

    // O accum rows are q = 4*hi + r: fetch that row's corr from lane (4*hi+r)
    float co[4];
    #pragma unroll
    for (int r = 0; r < 4; ++r) co[r] = __shfl(corr, hi * 4 + r);
    #pragma unroll
    for (int dc = 0; dc < 8; ++dc)
      #pragma unroll
      for (int r = 0; r < 4; ++r) o[dc][r] *= co[r];

    f16x4 pf;
    #pragma unroll
    for (int r = 0; r < 4; ++r) pf[r] = (f16)p[r];

    #pragma unroll
    for (int dc = 0; dc < 8; ++dc) {
      f16x4 vf;
      #pragma unroll
      for (int j = 0; j < 4; ++j)
        vf[j] = Vb[(size_t)(t + hi * 4 + j) * NQ + dc * 16 + lo];
      o[dc] = __builtin_amdgcn_mfma_f32_16x16x16f16(pf, vf, o[dc], 0, 0, 0);
    }
  }

  float inv[4];
  #pragma unroll
  for (int r = 0; r < 4; ++r) inv[r] = 1.f / __shfl(l_run, hi * 4 + r);

  const int tok0 = b * 2048 + q0;
  #pragma unroll
  for (int dc = 0; dc < 8; ++dc)
    #pragma unroll
    for (int r = 0; r < 4; ++r)
      outp[(size_t)(tok0 + hi * 4 + r) * KD + h * 128 + dc * 16 + lo] =
          (f16)(o[dc][r] * inv[r]);
}

// ---------------- launch ----------------
extern "C" void kernel_launch(void* const* d_in, const int* in_sizes, int n_in,
                              void* d_out, int out_size, void* d_ws, size_t ws_size,
                              hipStream_t stream) {
  const float* x      = (const float*)d_in[0];
  const float* wqkv_r = (const float*)d_in[1];
  const float* wqkv_i = (const float*)d_in[2];
  const float* bqkv_r = (const float*)d_in[3];
  const float* bqkv_i = (const float*)d_in[4];
  const float* wo_r   = (const float*)d_in[5];
  const float* wo_i   = (const float*)d_in[6];
  const float* bo_r   = (const float*)d_in[7];
  const float* bo_i   = (const float*)d_in[8];
  float* out = (float*)d_out;
  char* ws = (char*)d_ws;

  // workspace layout (96 MB total); Xh reused as attention output after GEMM1
  f16*   Wqkv_p = (f16*)(ws + 0);              // 6144*2048*2   = 25165824
  f16*   Wo_p   = (f16*)(ws + 25165824);       // 2048*2048*2   =  8388608
  float* biasq  = (float*)(ws + 33554432);     // 6144*4        =    24576
  float* biaso  = (float*)(ws + 33579008);     // 2048*4        =     8192
  f16*   qkv16  = (f16*)(ws + 33587200);       // 4096*6144*2   = 50331648
  f16*   Xh     = (f16*)(ws + 83918848);       // 4096*2048*2   = 16777216
  f16*   attn16 = Xh;                          // alias: X dead after GEMM1

  cast_x_kernel<<<(TOKENS * KD) / 256, 256, 0, stream>>>(x, Xh, TOKENS * KD);
  pack_wqkv_kernel<<<(NQ * KD) / 256, 256, 0, stream>>>(wqkv_r, wqkv_i, bqkv_r, bqkv_i,
                                                        Wqkv_p, biasq);
  pack_wo_kernel<<<(KD * KD) / 256, 256, 0, stream>>>(wo_r, wo_i, bo_r, bo_i, Wo_p, biaso);

  gemm_tn<true><<<dim3(NQ / 128, TOKENS / 128), 256, 0, stream>>>(Xh, Wqkv_p, biasq,
                                                                  (void*)qkv16, NQ);
  attn_kernel<<<dim3(2048 / 64, 32), 256, 0, stream>>>(qkv16, attn16);
  gemm_tn<false><<<dim3(KD / 128, TOKENS / 128), 256, 0, stream>>>(attn16, Wo_p, biaso,
                                                                   (void*)out, KD);
}